// Round 5
// baseline (347.000 us; speedup 1.0000x reference)
//
#include <hip/hip_runtime.h>
#include <hip/hip_bf16.h>
#include <stdint.h>

#define D_MODEL 1024
#define N_STATE 16
#define BATCH   4
#define SEQ     2048
#define M_ROWS  (BATCH*SEQ)      // 8192
#define H_FFN   (4*D_MODEL)      // 4096
#define NCHUNK  32
#define TCHUNK  (SEQ/NCHUNK)     // 64

typedef __attribute__((ext_vector_type(8))) short short8;
typedef __attribute__((ext_vector_type(4))) float f32x4;

// ---------- helpers ----------
__device__ __forceinline__ unsigned short f2bf(float f) {
  unsigned int u = __builtin_bit_cast(unsigned int, f);
  u += 0x7FFFu + ((u >> 16) & 1u);
  return (unsigned short)(u >> 16);
}

__device__ __forceinline__ void gload_lds16(const void* g, void* l) {
  __builtin_amdgcn_global_load_lds(
      (const __attribute__((address_space(1))) void*)g,
      (__attribute__((address_space(3))) void*)l,
      16, 0, 0);
}

// ---------- fp32 -> bf16 weight conversion ----------
__global__ __launch_bounds__(256)
void cvt_bf16(const float* __restrict__ in, unsigned short* __restrict__ out, int n4) {
  int i = blockIdx.x * 256 + threadIdx.x;
  if (i >= n4) return;
  float4 v = reinterpret_cast<const float4*>(in)[i];
  ushort4 o = { f2bf(v.x), f2bf(v.y), f2bf(v.z), f2bf(v.w) };
  reinterpret_cast<ushort4*>(out)[i] = o;
}

// ---------- LN stats only: per row -> (mu, inv_sigma) ----------
__global__ __launch_bounds__(256)
void ln_stats(const float* __restrict__ in, float2* __restrict__ stats) {
  const int row = blockIdx.x;
  const int tid = threadIdx.x;
  const float4 v = reinterpret_cast<const float4*>(in + (size_t)row * D_MODEL)[tid];
  float s  = v.x + v.y + v.z + v.w;
  float ss = v.x*v.x + v.y*v.y + v.z*v.z + v.w*v.w;
  #pragma unroll
  for (int o = 32; o > 0; o >>= 1) {
    s  += __shfl_down(s, o, 64);
    ss += __shfl_down(ss, o, 64);
  }
  __shared__ float red[8];
  const int wv = tid >> 6;
  if ((tid & 63) == 0) { red[wv] = s; red[4 + wv] = ss; }
  __syncthreads();
  if (tid == 0) {
    s  = red[0] + red[1] + red[2] + red[3];
    ss = red[4] + red[5] + red[6] + red[7];
    const float mu  = s * (1.0f / D_MODEL);
    const float inv = rsqrtf(ss * (1.0f / D_MODEL) - mu * mu + 1e-5f);
    stats[row] = make_float2(mu, inv);
  }
}

// ---------- full LayerNorm (LN2), bf16 out ----------
__global__ __launch_bounds__(256)
void ln_kernel_bf16(const float* __restrict__ in, const float* __restrict__ gamma,
                    const float* __restrict__ beta, unsigned short* __restrict__ outp) {
  const int row = blockIdx.x;
  const int tid = threadIdx.x;
  const float4 v = reinterpret_cast<const float4*>(in + (size_t)row * D_MODEL)[tid];
  float s  = v.x + v.y + v.z + v.w;
  float ss = v.x*v.x + v.y*v.y + v.z*v.z + v.w*v.w;
  #pragma unroll
  for (int o = 32; o > 0; o >>= 1) {
    s  += __shfl_down(s, o, 64);
    ss += __shfl_down(ss, o, 64);
  }
  __shared__ float red[8];
  const int wv = tid >> 6;
  if ((tid & 63) == 0) { red[wv] = s; red[4 + wv] = ss; }
  __syncthreads();
  s  = red[0] + red[1] + red[2] + red[3];
  ss = red[4] + red[5] + red[6] + red[7];
  const float mu  = s * (1.0f / D_MODEL);
  const float inv = rsqrtf(ss * (1.0f / D_MODEL) - mu * mu + 1e-5f);
  const float4 g4 = reinterpret_cast<const float4*>(gamma)[tid];
  const float4 b4 = reinterpret_cast<const float4*>(beta)[tid];
  ushort4 o = { f2bf((v.x - mu) * inv * g4.x + b4.x),
                f2bf((v.y - mu) * inv * g4.y + b4.y),
                f2bf((v.z - mu) * inv * g4.z + b4.z),
                f2bf((v.w - mu) * inv * g4.w + b4.w) };
  reinterpret_cast<ushort4*>(outp + (size_t)row * D_MODEL)[tid] = o;
}

// ---------- SSM scan, chunked (3 phases), LN1 fused via stats ----------
__global__ __launch_bounds__(256)
void scan_phase1(const float* __restrict__ x, const float2* __restrict__ stats,
                 const float* __restrict__ ln_w, const float* __restrict__ ln_b,
                 const float* __restrict__ A_log, const float* __restrict__ B_mat,
                 float* __restrict__ hend) {
  const int d = blockIdx.x * 256 + threadIdx.x;
  const int c = blockIdx.y;
  const int b = blockIdx.z;
  float a[16], Bm[16], h[16];
  const float4* Ar = reinterpret_cast<const float4*>(A_log + d * 16);
  const float4* Br = reinterpret_cast<const float4*>(B_mat + d * 16);
  #pragma unroll
  for (int i = 0; i < 4; i++) {
    const float4 av = Ar[i], bv = Br[i];
    a[4*i+0]=av.x; a[4*i+1]=av.y; a[4*i+2]=av.z; a[4*i+3]=av.w;
    Bm[4*i+0]=bv.x; Bm[4*i+1]=bv.y; Bm[4*i+2]=bv.z; Bm[4*i+3]=bv.w;
  }
  #pragma unroll
  for (int n = 0; n < 16; n++) { a[n] = 1.0f/(1.0f+__expf(-a[n])); h[n] = 0.0f; }
  const float gd = ln_w[d], bd = ln_b[d];

  const float* xp = x + ((size_t)b * SEQ + (size_t)c * TCHUNK) * D_MODEL + d;
  const float2* sp = stats + (size_t)b * SEQ + (size_t)c * TCHUNK;
  #pragma unroll 4
  for (int t = 0; t < TCHUNK; ++t) {
    const float2 st = sp[t];
    const float xv = (xp[(size_t)t * D_MODEL] - st.x) * st.y * gd + bd;
    #pragma unroll
    for (int n = 0; n < 16; n++) h[n] = a[n]*h[n] + Bm[n]*xv;
  }
  float* hp = hend + (((size_t)b * NCHUNK + c) * D_MODEL + d) * 16;
  #pragma unroll
  for (int i = 0; i < 4; i++) {
    float4 o = { h[4*i+0], h[4*i+1], h[4*i+2], h[4*i+3] };
    reinterpret_cast<float4*>(hp)[i] = o;
  }
}

__global__ __launch_bounds__(256)
void scan_phase2(const float* __restrict__ A_log, const float* __restrict__ hend,
                 float* __restrict__ carry) {
  const int idx = blockIdx.x * 256 + threadIdx.x;
  const int n = idx & 15;
  const int d = (idx >> 4) & (D_MODEL - 1);
  const int b = idx >> 14;
  const float a = 1.0f/(1.0f+__expf(-A_log[d*16+n]));
  float aT = a;
  #pragma unroll
  for (int i = 0; i < 6; i++) aT *= aT;   // a^64
  float cv = 0.0f;
  for (int c = 0; c < NCHUNK; c++) {
    const size_t off = (((size_t)b * NCHUNK + c) * D_MODEL + d) * 16 + n;
    carry[off] = cv;
    cv = aT * cv + hend[off];
  }
}

__global__ __launch_bounds__(256)
void scan_phase3(const float* __restrict__ x, const float2* __restrict__ stats,
                 const float* __restrict__ ln_w, const float* __restrict__ ln_b,
                 const float* __restrict__ A_log, const float* __restrict__ B_mat,
                 const float* __restrict__ C_mat, const float* __restrict__ D_vec,
                 const float* __restrict__ carry, unsigned short* __restrict__ ybf) {
  const int d = blockIdx.x * 256 + threadIdx.x;
  const int c = blockIdx.y;
  const int b = blockIdx.z;
  float a[16], Bm[16], Cm[16], h[16];
  const float4* Ar = reinterpret_cast<const float4*>(A_log + d * 16);
  const float4* Br = reinterpret_cast<const float4*>(B_mat + d * 16);
  const float4* Cr = reinterpret_cast<const float4*>(C_mat + d * 16);
  const float4* Hr = reinterpret_cast<const float4*>(carry + (((size_t)b * NCHUNK + c) * D_MODEL + d) * 16);
  #pragma unroll
  for (int i = 0; i < 4; i++) {
    const float4 av = Ar[i], bv = Br[i], cv = Cr[i], hv = Hr[i];
    a[4*i+0]=av.x; a[4*i+1]=av.y; a[4*i+2]=av.z; a[4*i+3]=av.w;
    Bm[4*i+0]=bv.x; Bm[4*i+1]=bv.y; Bm[4*i+2]=bv.z; Bm[4*i+3]=bv.w;
    Cm[4*i+0]=cv.x; Cm[4*i+1]=cv.y; Cm[4*i+2]=cv.z; Cm[4*i+3]=cv.w;
    h[4*i+0]=hv.x; h[4*i+1]=hv.y; h[4*i+2]=hv.z; h[4*i+3]=hv.w;
  }
  #pragma unroll
  for (int n = 0; n < 16; n++) a[n] = 1.0f/(1.0f+__expf(-a[n]));
  const float Dv = D_vec[d];
  const float gd = ln_w[d], bd = ln_b[d];

  const float* xp = x + ((size_t)b * SEQ + (size_t)c * TCHUNK) * D_MODEL + d;
  const float2* sp = stats + (size_t)b * SEQ + (size_t)c * TCHUNK;
  unsigned short* yp = ybf + ((size_t)b * SEQ + (size_t)c * TCHUNK) * D_MODEL + d;
  #pragma unroll 4
  for (int t = 0; t < TCHUNK; ++t) {
    const float2 st = sp[t];
    const float xv = (xp[(size_t)t * D_MODEL] - st.x) * st.y * gd + bd;
    float y = Dv * xv;
    #pragma unroll
    for (int n = 0; n < 16; n++) {
      h[n] = a[n]*h[n] + Bm[n]*xv;
      y += Cm[n]*h[n];
    }
    yp[(size_t)t * D_MODEL] = f2bf(y / (1.0f + __expf(-y)));
  }
}

// ---------- triple-buffered bf16 MFMA GEMM (deep wait slack) ----------
// C[M,N] = epi(A[M,K] @ Bt[N,K]^T + bias). BM=128, BN=256, BK=64.
// 512 thr = 8 waves (2M x 4N); per-wave output 64x64 (4x4 16x16x32 frags).
// Triple-buffered LDS (144KB): at tile t, stage tile t+2 (6 gload_lds/wave),
// compute tile t with NO intra-tile barriers, then ONE counted vmcnt(6)
// (waits only for tile t+1, staged a full tile earlier) + ONE s_barrier.
// XOR-swizzled LDS (conflict-free ds_read_b128), XCD-aware block swizzle,
// LDS-slab coalesced epilogue.
template<int ACT, bool RES, typename OutT>
__global__ __launch_bounds__(512, 2)
void gemm_tb(const unsigned short* __restrict__ A, const unsigned short* __restrict__ Bt,
             const float* __restrict__ bias, const float* __restrict__ res,
             OutT* __restrict__ C, int M, int N, int K) {
  constexpr int BM = 128, BN = 256, BK = 64;
  __shared__ __align__(128) unsigned short As[3 * BM * BK];   // 48KB
  __shared__ __align__(128) unsigned short Bs[3 * BN * BK];   // 96KB

  const int tid = threadIdx.x;
  const int l = tid & 63, w = tid >> 6;
  const int wr = w >> 2, wn = w & 3;

  // XCD-aware chunked swizzle (grids are multiples of 8)
  int bid = blockIdx.x;
  const int cpx = gridDim.x >> 3;
  bid = (bid & 7) * cpx + (bid >> 3);
  const int nbx = N / BN;
  const int bn = (bid % nbx) * BN;
  const int bm = (bid / nbx) * BM;

  // staging: part = 64 rows x 64 cols (8KB). Wave w stages rows 8w..8w+7 of
  // each part; lane l -> row 8w+(l>>3), 16B chunk (l&7) (LDS linear).
  // Source byte pre-swizzled: LDS[row][kb] = global[row][kb ^ ((row&7)<<4)].
  const int prow = l >> 3;
  const int skb  = ((l & 7) ^ prow) << 4;
  const char* Ag = (const char*)A  + ((size_t)(bm + 8 * w + prow) * K) * 2 + skb;
  const char* Bg = (const char*)Bt + ((size_t)(bn + 8 * w + prow) * K) * 2 + skb;

#define STA(buf, q, k0) gload_lds16(Ag + ((size_t)(q)*64*K + (k0))*2, \
                                    (char*)As + (buf)*16384 + (q)*8192 + w*1024)
#define STB(buf, q, k0) gload_lds16(Bg + ((size_t)(q)*64*K + (k0))*2, \
                                    (char*)Bs + (buf)*32768 + (q)*8192 + w*1024)
  auto stage = [&](int buf, int k0) {
    STA(buf, 0, k0); STA(buf, 1, k0);
    STB(buf, 0, k0); STB(buf, 1, k0); STB(buf, 2, k0); STB(buf, 3, k0);
  };

  // read-side: frag addr = base + row*128 + ((kk*64 + (l>>4)*16) ^ ((l&7)<<4))
  const int xk0 = ((l >> 4) * 16) ^ ((l & 7) << 4);
  const int xk1 = (64 + (l >> 4) * 16) ^ ((l & 7) << 4);
  const char* ArB = (const char*)As + (wr * 64 + (l & 15)) * 128;
  const char* BrB = (const char*)Bs + (wn * 64 + (l & 15)) * 128;

  f32x4 acc[4][4] = {};

  const int NT = K / BK;
  // prologue: tiles 0,1 -> bufs 0,1
  stage(0, 0);
  stage(1, BK);
  asm volatile("s_waitcnt vmcnt(6)" ::: "memory");   // tile 0 landed
  __builtin_amdgcn_s_barrier();
  asm volatile("" ::: "memory");

  int cb = 0, sb = 2;
  for (int t = 0; t < NT; ++t) {
    const bool st = (t + 2) < NT;
    if (st) stage(sb, (t + 2) * BK);

    const char* Ap = ArB + cb * 16384;
    const char* Bp = BrB + cb * 32768;
    #pragma unroll
    for (int kk = 0; kk < 2; ++kk) {
      const int xk = kk ? xk1 : xk0;
      short8 af[4], bv[4];
      #pragma unroll
      for (int m = 0; m < 4; ++m)
        af[m] = *reinterpret_cast<const short8*>(Ap + m * 2048 + xk);
      #pragma unroll
      for (int n = 0; n < 4; ++n)
        bv[n] = *reinterpret_cast<const short8*>(Bp + n * 2048 + xk);
      __builtin_amdgcn_s_setprio(1);
      #pragma unroll
      for (int m = 0; m < 4; ++m)
        #pragma unroll
        for (int n = 0; n < 4; ++n)
          acc[m][n] = __builtin_amdgcn_mfma_f32_16x16x32_bf16(af[m], bv[n], acc[m][n], 0, 0, 0);
      __builtin_amdgcn_s_setprio(0);
    }

    if (st) asm volatile("s_waitcnt vmcnt(6) lgkmcnt(0)" ::: "memory");  // t+1 landed
    else    asm volatile("s_waitcnt vmcnt(0) lgkmcnt(0)" ::: "memory");  // drain tail
    __builtin_amdgcn_s_barrier();
    asm volatile("" ::: "memory");
    cb = (cb == 2) ? 0 : cb + 1;
    sb = (sb == 2) ? 0 : sb + 1;
  }
#undef STA
#undef STB

  // ---- coalesced epilogue via wave-private LDS slab (reuses As) ----
  constexpr int LPAD = 65;                      // floats per slab row (+1 pad)
  float* slab = (float*)((char*)As + w * 4352); // 16*65*4=4160 -> 4352 stride
  const int fr = (l >> 4) * 4;
  const int fc = l & 15;
  const int rdrow = l >> 4;                     // 64 cols -> 16 chunks/row
  const int rdchk = l & 15;
  const int colg0 = bn + wn * 64;
  float bvn[4];
  #pragma unroll
  for (int n = 0; n < 4; ++n) bvn[n] = bias[colg0 + n * 16 + fc];

  #pragma unroll
  for (int m = 0; m < 4; ++m) {
    asm volatile("s_waitcnt lgkmcnt(0)" ::: "memory");  // prev readback done
    #pragma unroll
    for (int n = 0; n < 4; ++n)
      #pragma unroll
      for (int r = 0; r < 4; ++r)
        slab[(fr + r) * LPAD + n * 16 + fc] = acc[m][n][r] + bvn[n];
    asm volatile("s_waitcnt lgkmcnt(0)" ::: "memory");  // writes visible to wave
    const int row0 = bm + wr * 64 + m * 16;
    #pragma unroll
    for (int p = 0; p < 4; ++p) {
      const int row = p * 4 + rdrow;
      float4 v4 = *reinterpret_cast<const float4*>(&slab[row * LPAD + rdchk * 4]);
      const size_t idx = (size_t)(row0 + row) * N + colg0 + rdchk * 4;
      float vv[4] = { v4.x, v4.y, v4.z, v4.w };
      if (ACT == 1) {
        #pragma unroll
        for (int j = 0; j < 4; ++j)
          vv[j] = 0.5f * vv[j] * (1.0f + erff(vv[j] * 0.70710678118f));
      }
      if (RES) {
        const float4 r4 = *reinterpret_cast<const float4*>(&res[idx]);
        vv[0] += r4.x; vv[1] += r4.y; vv[2] += r4.z; vv[3] += r4.w;
      }
      if constexpr (sizeof(OutT) == 2) {
        ushort4 o = { f2bf(vv[0]), f2bf(vv[1]), f2bf(vv[2]), f2bf(vv[3]) };
        *reinterpret_cast<ushort4*>(&C[idx]) = o;
      } else {
        float4 o = { vv[0], vv[1], vv[2], vv[3] };
        *reinterpret_cast<float4*>(&C[idx]) = o;
      }
    }
  }
}

// ---------- launch ----------
extern "C" void kernel_launch(void* const* d_in, const int* in_sizes, int n_in,
                              void* d_out, int out_size, void* d_ws, size_t ws_size,
                              hipStream_t stream) {
  const float* x      = (const float*)d_in[0];
  const float* ln_w   = (const float*)d_in[1];
  const float* ln_b   = (const float*)d_in[2];
  const float* A_log  = (const float*)d_in[3];
  const float* B_mat  = (const float*)d_in[4];
  const float* C_mat  = (const float*)d_in[5];
  const float* D_vec  = (const float*)d_in[6];
  const float* out_w  = (const float*)d_in[7];
  const float* out_b  = (const float*)d_in[8];
  const float* ln2_w  = (const float*)d_in[9];
  const float* ln2_b  = (const float*)d_in[10];
  const float* ffn1_w = (const float*)d_in[11];
  const float* ffn1_b = (const float*)d_in[12];
  const float* ffn2_w = (const float*)d_in[13];
  const float* ffn2_b = (const float*)d_in[14];
  float* out = (float*)d_out;

  char* ws = (char*)d_ws;
  const size_t MB = 1u << 20;
  float*          x1    = (float*)(ws);                    // 32MB (GEMM1 out)
  unsigned short* ybf   = (unsigned short*)(ws + 32*MB);   // 16MB; reused as xn2
  unsigned short* hdn   = (unsigned short*)(ws + 48*MB);   // 64MB
  unsigned short* w1b   = (unsigned short*)(ws + 112*MB);  // 2MB
  unsigned short* w2b   = (unsigned short*)(ws + 114*MB);  // 8MB
  unsigned short* w3b   = (unsigned short*)(ws + 122*MB);  // 8MB
  float*          hend  = (float*)(ws + 130*MB);           // 8MB
  float*          carry = (float*)(ws + 138*MB);           // 8MB
  float2*         stats = (float2*)(ws + 146*MB);          // 64KB

  // weights -> bf16
  cvt_bf16<<<(D_MODEL*D_MODEL/4)/256, 256, 0, stream>>>(out_w,  w1b, D_MODEL*D_MODEL/4);
  cvt_bf16<<<(H_FFN*D_MODEL/4)/256,  256, 0, stream>>>(ffn1_w, w2b, H_FFN*D_MODEL/4);
  cvt_bf16<<<(H_FFN*D_MODEL/4)/256,  256, 0, stream>>>(ffn2_w, w3b, H_FFN*D_MODEL/4);

  // LN1 stats (normalize fused into scan)
  ln_stats<<<M_ROWS, 256, 0, stream>>>(x, stats);

  // SSM scan -> ybf = silu(y) bf16
  dim3 gscan(D_MODEL/256, NCHUNK, BATCH);
  scan_phase1<<<gscan, 256, 0, stream>>>(x, stats, ln_w, ln_b, A_log, B_mat, hend);
  scan_phase2<<<(BATCH*D_MODEL*N_STATE)/256, 256, 0, stream>>>(A_log, hend, carry);
  scan_phase3<<<gscan, 256, 0, stream>>>(x, stats, ln_w, ln_b, A_log, B_mat, C_mat,
                                         D_vec, carry, ybf);

  // GEMM1: x1 = x + silu_y @ out_w^T + out_b   (grid 256)
  gemm_tb<0, true, float><<<dim3((M_ROWS/128)*(D_MODEL/256)), 512, 0, stream>>>(
      ybf, w1b, out_b, x, x1, M_ROWS, D_MODEL, D_MODEL);

  // LN2: xn2 = LN(x1) bf16 (into ybf buffer)
  ln_kernel_bf16<<<M_ROWS, 256, 0, stream>>>(x1, ln2_w, ln2_b, ybf);

  // GEMM2: hdn = gelu(xn2 @ ffn1^T + ffn1_b) bf16  (grid 1024)
  gemm_tb<1, false, unsigned short><<<dim3((M_ROWS/128)*(H_FFN/256)), 512, 0, stream>>>(
      ybf, w2b, ffn1_b, nullptr, hdn, M_ROWS, H_FFN, D_MODEL);

  // GEMM3: out = x1 + hdn @ ffn2^T + ffn2_b (grid 256)
  gemm_tb<0, true, float><<<dim3((M_ROWS/128)*(D_MODEL/256)), 512, 0, stream>>>(
      hdn, w3b, ffn2_b, x1, out, M_ROWS, D_MODEL, H_FFN);
}

// Round 8
// 307.356 us; speedup vs baseline: 1.1290x; 1.1290x over previous
//
#include <hip/hip_runtime.h>
#include <hip/hip_bf16.h>
#include <stdint.h>

#define D_MODEL 1024
#define N_STATE 16
#define BATCH   4
#define SEQ     2048
#define M_ROWS  (BATCH*SEQ)      // 8192
#define H_FFN   (4*D_MODEL)      // 4096
#define NCHUNK  32
#define TCHUNK  (SEQ/NCHUNK)     // 64

typedef __attribute__((ext_vector_type(8))) short short8;
typedef __attribute__((ext_vector_type(4))) float f32x4;

// ---------- helpers ----------
__device__ __forceinline__ unsigned short f2bf(float f) {
  unsigned int u = __builtin_bit_cast(unsigned int, f);
  u += 0x7FFFu + ((u >> 16) & 1u);
  return (unsigned short)(u >> 16);
}

__device__ __forceinline__ void gload_lds16(const void* g, void* l) {
  __builtin_amdgcn_global_load_lds(
      (const __attribute__((address_space(1))) void*)g,
      (__attribute__((address_space(3))) void*)l,
      16, 0, 0);
}

// ---------- fp32 -> bf16 weight conversion ----------
__global__ __launch_bounds__(256)
void cvt_bf16(const float* __restrict__ in, unsigned short* __restrict__ out, int n4) {
  int i = blockIdx.x * 256 + threadIdx.x;
  if (i >= n4) return;
  float4 v = reinterpret_cast<const float4*>(in)[i];
  ushort4 o = { f2bf(v.x), f2bf(v.y), f2bf(v.z), f2bf(v.w) };
  reinterpret_cast<ushort4*>(out)[i] = o;
}

// ---------- LN stats only: per row -> (mu, inv_sigma) ----------
__global__ __launch_bounds__(256)
void ln_stats(const float* __restrict__ in, float2* __restrict__ stats) {
  const int row = blockIdx.x;
  const int tid = threadIdx.x;
  const float4 v = reinterpret_cast<const float4*>(in + (size_t)row * D_MODEL)[tid];
  float s  = v.x + v.y + v.z + v.w;
  float ss = v.x*v.x + v.y*v.y + v.z*v.z + v.w*v.w;
  #pragma unroll
  for (int o = 32; o > 0; o >>= 1) {
    s  += __shfl_down(s, o, 64);
    ss += __shfl_down(ss, o, 64);
  }
  __shared__ float red[8];
  const int wv = tid >> 6;
  if ((tid & 63) == 0) { red[wv] = s; red[4 + wv] = ss; }
  __syncthreads();
  if (tid == 0) {
    s  = red[0] + red[1] + red[2] + red[3];
    ss = red[4] + red[5] + red[6] + red[7];
    const float mu  = s * (1.0f / D_MODEL);
    const float inv = rsqrtf(ss * (1.0f / D_MODEL) - mu * mu + 1e-5f);
    stats[row] = make_float2(mu, inv);
  }
}

// ---------- full LayerNorm (LN2), bf16 out ----------
__global__ __launch_bounds__(256)
void ln_kernel_bf16(const float* __restrict__ in, const float* __restrict__ gamma,
                    const float* __restrict__ beta, unsigned short* __restrict__ outp) {
  const int row = blockIdx.x;
  const int tid = threadIdx.x;
  const float4 v = reinterpret_cast<const float4*>(in + (size_t)row * D_MODEL)[tid];
  float s  = v.x + v.y + v.z + v.w;
  float ss = v.x*v.x + v.y*v.y + v.z*v.z + v.w*v.w;
  #pragma unroll
  for (int o = 32; o > 0; o >>= 1) {
    s  += __shfl_down(s, o, 64);
    ss += __shfl_down(ss, o, 64);
  }
  __shared__ float red[8];
  const int wv = tid >> 6;
  if ((tid & 63) == 0) { red[wv] = s; red[4 + wv] = ss; }
  __syncthreads();
  s  = red[0] + red[1] + red[2] + red[3];
  ss = red[4] + red[5] + red[6] + red[7];
  const float mu  = s * (1.0f / D_MODEL);
  const float inv = rsqrtf(ss * (1.0f / D_MODEL) - mu * mu + 1e-5f);
  const float4 g4 = reinterpret_cast<const float4*>(gamma)[tid];
  const float4 b4 = reinterpret_cast<const float4*>(beta)[tid];
  ushort4 o = { f2bf((v.x - mu) * inv * g4.x + b4.x),
                f2bf((v.y - mu) * inv * g4.y + b4.y),
                f2bf((v.z - mu) * inv * g4.z + b4.z),
                f2bf((v.w - mu) * inv * g4.w + b4.w) };
  reinterpret_cast<ushort4*>(outp + (size_t)row * D_MODEL)[tid] = o;
}

// ---------- SSM scan, chunked (3 phases), LN1 fused via stats ----------
__global__ __launch_bounds__(256)
void scan_phase1(const float* __restrict__ x, const float2* __restrict__ stats,
                 const float* __restrict__ ln_w, const float* __restrict__ ln_b,
                 const float* __restrict__ A_log, const float* __restrict__ B_mat,
                 float* __restrict__ hend) {
  const int d = blockIdx.x * 256 + threadIdx.x;
  const int c = blockIdx.y;
  const int b = blockIdx.z;
  float a[16], Bm[16], h[16];
  const float4* Ar = reinterpret_cast<const float4*>(A_log + d * 16);
  const float4* Br = reinterpret_cast<const float4*>(B_mat + d * 16);
  #pragma unroll
  for (int i = 0; i < 4; i++) {
    const float4 av = Ar[i], bv = Br[i];
    a[4*i+0]=av.x; a[4*i+1]=av.y; a[4*i+2]=av.z; a[4*i+3]=av.w;
    Bm[4*i+0]=bv.x; Bm[4*i+1]=bv.y; Bm[4*i+2]=bv.z; Bm[4*i+3]=bv.w;
  }
  #pragma unroll
  for (int n = 0; n < 16; n++) { a[n] = 1.0f/(1.0f+__expf(-a[n])); h[n] = 0.0f; }
  const float gd = ln_w[d], bd = ln_b[d];

  const float* xp = x + ((size_t)b * SEQ + (size_t)c * TCHUNK) * D_MODEL + d;
  const float2* sp = stats + (size_t)b * SEQ + (size_t)c * TCHUNK;
  #pragma unroll 4
  for (int t = 0; t < TCHUNK; ++t) {
    const float2 st = sp[t];
    const float xv = (xp[(size_t)t * D_MODEL] - st.x) * st.y * gd + bd;
    #pragma unroll
    for (int n = 0; n < 16; n++) h[n] = a[n]*h[n] + Bm[n]*xv;
  }
  float* hp = hend + (((size_t)b * NCHUNK + c) * D_MODEL + d) * 16;
  #pragma unroll
  for (int i = 0; i < 4; i++) {
    float4 o = { h[4*i+0], h[4*i+1], h[4*i+2], h[4*i+3] };
    reinterpret_cast<float4*>(hp)[i] = o;
  }
}

__global__ __launch_bounds__(256)
void scan_phase2(const float* __restrict__ A_log, const float* __restrict__ hend,
                 float* __restrict__ carry) {
  const int idx = blockIdx.x * 256 + threadIdx.x;
  const int n = idx & 15;
  const int d = (idx >> 4) & (D_MODEL - 1);
  const int b = idx >> 14;
  const float a = 1.0f/(1.0f+__expf(-A_log[d*16+n]));
  float aT = a;
  #pragma unroll
  for (int i = 0; i < 6; i++) aT *= aT;   // a^64
  float cv = 0.0f;
  for (int c = 0; c < NCHUNK; c++) {
    const size_t off = (((size_t)b * NCHUNK + c) * D_MODEL + d) * 16 + n;
    carry[off] = cv;
    cv = aT * cv + hend[off];
  }
}

__global__ __launch_bounds__(256)
void scan_phase3(const float* __restrict__ x, const float2* __restrict__ stats,
                 const float* __restrict__ ln_w, const float* __restrict__ ln_b,
                 const float* __restrict__ A_log, const float* __restrict__ B_mat,
                 const float* __restrict__ C_mat, const float* __restrict__ D_vec,
                 const float* __restrict__ carry, unsigned short* __restrict__ ybf) {
  const int d = blockIdx.x * 256 + threadIdx.x;
  const int c = blockIdx.y;
  const int b = blockIdx.z;
  float a[16], Bm[16], Cm[16], h[16];
  const float4* Ar = reinterpret_cast<const float4*>(A_log + d * 16);
  const float4* Br = reinterpret_cast<const float4*>(B_mat + d * 16);
  const float4* Cr = reinterpret_cast<const float4*>(C_mat + d * 16);
  const float4* Hr = reinterpret_cast<const float4*>(carry + (((size_t)b * NCHUNK + c) * D_MODEL + d) * 16);
  #pragma unroll
  for (int i = 0; i < 4; i++) {
    const float4 av = Ar[i], bv = Br[i], cv = Cr[i], hv = Hr[i];
    a[4*i+0]=av.x; a[4*i+1]=av.y; a[4*i+2]=av.z; a[4*i+3]=av.w;
    Bm[4*i+0]=bv.x; Bm[4*i+1]=bv.y; Bm[4*i+2]=bv.z; Bm[4*i+3]=bv.w;
    Cm[4*i+0]=cv.x; Cm[4*i+1]=cv.y; Cm[4*i+2]=cv.z; Cm[4*i+3]=cv.w;
    h[4*i+0]=hv.x; h[4*i+1]=hv.y; h[4*i+2]=hv.z; h[4*i+3]=hv.w;
  }
  #pragma unroll
  for (int n = 0; n < 16; n++) a[n] = 1.0f/(1.0f+__expf(-a[n]));
  const float Dv = D_vec[d];
  const float gd = ln_w[d], bd = ln_b[d];

  const float* xp = x + ((size_t)b * SEQ + (size_t)c * TCHUNK) * D_MODEL + d;
  const float2* sp = stats + (size_t)b * SEQ + (size_t)c * TCHUNK;
  unsigned short* yp = ybf + ((size_t)b * SEQ + (size_t)c * TCHUNK) * D_MODEL + d;
  #pragma unroll 4
  for (int t = 0; t < TCHUNK; ++t) {
    const float2 st = sp[t];
    const float xv = (xp[(size_t)t * D_MODEL] - st.x) * st.y * gd + bd;
    float y = Dv * xv;
    #pragma unroll
    for (int n = 0; n < 16; n++) {
      h[n] = a[n]*h[n] + Bm[n]*xv;
      y += Cm[n]*h[n];
    }
    yp[(size_t)t * D_MODEL] = f2bf(y / (1.0f + __expf(-y)));
  }
}

// ---------- m201-schedule bf16 MFMA GEMM (region-safe staging) ----------
// C[M,N] = epi(A[M,K] @ Bt[N,K]^T + bias). BN=256, BK=64, BM in {256,128}.
// 512 thr = 8 waves (2M x 4N); per-wave output (BM/2) x 64.
// LDS: 2 buffers each for A (BM x 64) and B (256 x 64); 64-row "parts".
// Read zigzag per tile: p0 (mh0,nh0) -> p1 (mh0,nh1) -> p2 (mh1,nh1) -> p3 (mh1,nh0).
// Last-read phase per part (BM=256): A parts {0,2} p0; A parts {1,3} p2; all B p1.
// (BM=128): both A parts p2; all B p1.
// Stage stream per tile k, ALL targeting tile k+2 (same buffer as k):
//   p1: A{0,2}   (consumed p0, 1 barrier earlier)         [BM=256 only]
//   p2: B{0..3}  (consumed p1)
//   p3: A{1,3} (or A{0,1} for BM=128), then vmcnt(NLW)  -> tile k+1 fully landed.
// Every load gets 6-7 phases (~2000 cyc) of slack; one counted wait per tile.
template<int BM, int ACT, bool RES, typename OutT>
__global__ __launch_bounds__(512, 2)
void gemm_hk(const unsigned short* __restrict__ A, const unsigned short* __restrict__ Bt,
             const float* __restrict__ bias, const float* __restrict__ res,
             OutT* __restrict__ C, int M, int N, int K) {
  constexpr int BN = 256, BK = 64;
  constexpr int MH2 = BM / 64;                // A m-frags per half (4 or 2)
  constexpr int ABUFB = BM * 128;             // bytes per A buffer
  constexpr int BBUFB = BN * 128;             // bytes per B buffer
  constexpr int NLW = (BM == 256) ? 8 : 6;    // loads per K-tile per wave
  __shared__ unsigned short As[2 * BM * 64];
  __shared__ unsigned short Bs[2 * BN * 64];

  const int tid = threadIdx.x;
  const int l = tid & 63, w = tid >> 6;
  const int wr = w >> 2, wn = w & 3;

  // XCD-aware chunked swizzle (grids are multiples of 8)
  int bid = blockIdx.x;
  const int cpx = gridDim.x >> 3;
  bid = (bid & 7) * cpx + (bid >> 3);
  const int nbx = N / BN;
  const int bn = (bid % nbx) * BN;
  const int bm = (bid / nbx) * BM;

  // staging (R3-verified): part = 64 rows x 128B; wave w writes rows 8w..8w+7,
  // lane l -> row 8w+(l>>3), LDS byte (l&7)*16 (linear dest). Source byte
  // pre-swizzled so LDS[row][kb] = global[row][kb ^ ((row&7)<<4)].
  const int prow = l >> 3;
  const int skb  = ((l & 7) ^ prow) << 4;
  const char* Ag = (const char*)A  + ((size_t)(bm + 8 * w + prow) * K) * 2 + skb;
  const char* Bg = (const char*)Bt + ((size_t)(bn + 8 * w + prow) * K) * 2 + skb;

#define STA(kt, q, k0) gload_lds16(Ag + ((size_t)(q)*64*K + (k0))*2, \
                                   (char*)As + ((kt)&1)*ABUFB + (q)*8192 + w*1024)
#define STB(kt, q, k0) gload_lds16(Bg + ((size_t)(q)*64*K + (k0))*2, \
                                   (char*)Bs + ((kt)&1)*BBUFB + (q)*8192 + w*1024)

  // read-side: frag addr = base + row*128 + ((kk*64 + (l>>4)*16) ^ ((l&7)<<4))
  const int xk0 = ((l >> 4) * 16) ^ ((l & 7) << 4);
  const int xk1 = (64 + (l >> 4) * 16) ^ ((l & 7) << 4);
  const char* ArB = (const char*)As + (wr * (BM / 2) + (l & 15)) * 128;
  const char* BrB = (const char*)Bs + (wn * 64 + (l & 15)) * 128;

  f32x4 acc[2 * MH2][4] = {};
  short8 af[MH2][2], bf0[2][2], bf1[2][2];

#define READ_A(c, mh)                                                          \
  _Pragma("unroll")                                                            \
  for (int i = 0; i < MH2; ++i) {                                              \
    const char* p = ArB + (c) * ABUFB + ((mh) * (BM / 4) + i * 16) * 128;      \
    af[i][0] = *reinterpret_cast<const short8*>(p + xk0);                      \
    af[i][1] = *reinterpret_cast<const short8*>(p + xk1);                      \
  }
#define READ_B(c, nh, dst)                                                     \
  _Pragma("unroll")                                                            \
  for (int j = 0; j < 2; ++j) {                                                \
    const char* p = BrB + (c) * BBUFB + ((nh) * 32 + j * 16) * 128;            \
    dst[j][0] = *reinterpret_cast<const short8*>(p + xk0);                     \
    dst[j][1] = *reinterpret_cast<const short8*>(p + xk1);                     \
  }
#define MFMA_Q(mh, nh, bsrc)                                                   \
  __builtin_amdgcn_s_setprio(1);                                               \
  _Pragma("unroll")                                                            \
  for (int i = 0; i < MH2; ++i)                                                \
    _Pragma("unroll")                                                          \
    for (int j = 0; j < 2; ++j) {                                              \
      acc[(mh)*MH2+i][(nh)*2+j] = __builtin_amdgcn_mfma_f32_16x16x32_bf16(     \
          af[i][0], bsrc[j][0], acc[(mh)*MH2+i][(nh)*2+j], 0, 0, 0);           \
      acc[(mh)*MH2+i][(nh)*2+j] = __builtin_amdgcn_mfma_f32_16x16x32_bf16(     \
          af[i][1], bsrc[j][1], acc[(mh)*MH2+i][(nh)*2+j], 0, 0, 0);           \
    }                                                                          \
  __builtin_amdgcn_s_setprio(0);
#define SYNC_IN()                                                              \
  __builtin_amdgcn_s_barrier();                                                \
  asm volatile("s_waitcnt lgkmcnt(0)" ::: "memory");                           \
  __builtin_amdgcn_sched_barrier(0);
#define SYNC_OUT() __builtin_amdgcn_s_barrier();

  // full-tile stage in the in-loop issue order (A-early parts, B, A-late parts)
#define STAGE_TILE(kt, k0)                                                     \
  if constexpr (BM == 256) {                                                   \
    STA(kt, 0, k0); STA(kt, 2, k0);                                            \
    STB(kt, 0, k0); STB(kt, 1, k0); STB(kt, 2, k0); STB(kt, 3, k0);            \
    STA(kt, 1, k0); STA(kt, 3, k0);                                            \
  } else {                                                                     \
    STB(kt, 0, k0); STB(kt, 1, k0); STB(kt, 2, k0); STB(kt, 3, k0);            \
    STA(kt, 0, k0); STA(kt, 1, k0);                                            \
  }

  const int NT = K / BK;
  // prologue: tiles 0 and 1 fully staged; wait for tile 0 (NLW of tile 1 remain)
  STAGE_TILE(0, 0)
  STAGE_TILE(1, BK)
  asm volatile("s_waitcnt vmcnt(%0)" :: "i"(NLW) : "memory");
  __builtin_amdgcn_s_barrier();

  for (int k = 0; k < NT; ++k) {
    const int c = k & 1;
    const int kn2 = (k + 2) * BK;
    const bool st = (k + 2) < NT;
    // p0: reads A-half0 + B-half0 ; MFMA (0,0)
    READ_A(c, 0); READ_B(c, 0, bf0);
    SYNC_IN(); MFMA_Q(0, 0, bf0); SYNC_OUT();
    // p1: reads B-half1 ; stage (k+2).A parts last-read-at-p0 ; MFMA (0,1)
    READ_B(c, 1, bf1);
    if (st) { if constexpr (BM == 256) { STA(k + 2, 0, kn2); STA(k + 2, 2, kn2); } }
    SYNC_IN(); MFMA_Q(0, 1, bf1); SYNC_OUT();
    // p2: reads A-half1 ; stage (k+2).B all (last read p1) ; MFMA (1,1)
    READ_A(c, 1);
    if (st) { STB(k + 2, 0, kn2); STB(k + 2, 1, kn2); STB(k + 2, 2, kn2); STB(k + 2, 3, kn2); }
    SYNC_IN(); MFMA_Q(1, 1, bf1); SYNC_OUT();
    // p3: stage (k+2).A parts last-read-at-p2 ; counted wait ; MFMA (1,0)
    if (st) {
      if constexpr (BM == 256) { STA(k + 2, 1, kn2); STA(k + 2, 3, kn2); }
      else                     { STA(k + 2, 0, kn2); STA(k + 2, 1, kn2); }
      asm volatile("s_waitcnt vmcnt(%0)" :: "i"(NLW) : "memory");
    } else if (k + 1 < NT) {
      asm volatile("s_waitcnt vmcnt(0)" ::: "memory");
    }
    SYNC_IN(); MFMA_Q(1, 0, bf0); SYNC_OUT();
  }
#undef STA
#undef STB
#undef STAGE_TILE
#undef READ_A
#undef READ_B
#undef MFMA_Q
#undef SYNC_IN
#undef SYNC_OUT

  // ---- coalesced epilogue via wave-private LDS slab (reuses Bs) ----
  // Safe: after the loop's final barrier every wave has executed its last
  // lgkmcnt(0), so all LDS reads are retired; vmcnt(0) at k=NT-2 retired all
  // gload_lds writes. Slabs are wave-private.
  constexpr int MFR = 2 * MH2;                  // total m-frags (8 or 4)
  constexpr int LPAD = 65;                      // floats per slab row (+1 pad)
  float* slab = (float*)((char*)Bs + w * 4352); // 8 waves x 4352B <= 64KB
  const int fr = (l >> 4) * 4;
  const int fc = l & 15;
  const int rdrow = l >> 4;                     // 16 float4 chunks per row
  const int rdchk = l & 15;
  const int colg0 = bn + wn * 64;
  float bvn[4];
  #pragma unroll
  for (int n = 0; n < 4; ++n) bvn[n] = bias[colg0 + n * 16 + fc];

  #pragma unroll
  for (int m = 0; m < MFR; ++m) {
    asm volatile("s_waitcnt lgkmcnt(0)" ::: "memory");  // prev readback done
    #pragma unroll
    for (int n = 0; n < 4; ++n)
      #pragma unroll
      for (int r = 0; r < 4; ++r)
        slab[(fr + r) * LPAD + n * 16 + fc] = acc[m][n][r] + bvn[n];
    asm volatile("s_waitcnt lgkmcnt(0)" ::: "memory");  // writes visible to wave
    const int row0 = bm + wr * (BM / 2) + m * 16;
    #pragma unroll
    for (int p = 0; p < 4; ++p) {
      const int row = p * 4 + rdrow;
      float4 v4 = *reinterpret_cast<const float4*>(&slab[row * LPAD + rdchk * 4]);
      const size_t idx = (size_t)(row0 + row) * N + colg0 + rdchk * 4;
      float vv[4] = { v4.x, v4.y, v4.z, v4.w };
      if (ACT == 1) {
        #pragma unroll
        for (int j = 0; j < 4; ++j)
          vv[j] = 0.5f * vv[j] * (1.0f + erff(vv[j] * 0.70710678118f));
      }
      if (RES) {
        const float4 r4 = *reinterpret_cast<const float4*>(&res[idx]);
        vv[0] += r4.x; vv[1] += r4.y; vv[2] += r4.z; vv[3] += r4.w;
      }
      if constexpr (sizeof(OutT) == 2) {
        ushort4 o = { f2bf(vv[0]), f2bf(vv[1]), f2bf(vv[2]), f2bf(vv[3]) };
        *reinterpret_cast<ushort4*>(&C[idx]) = o;
      } else {
        float4 o = { vv[0], vv[1], vv[2], vv[3] };
        *reinterpret_cast<float4*>(&C[idx]) = o;
      }
    }
  }
}

// ---------- launch ----------
extern "C" void kernel_launch(void* const* d_in, const int* in_sizes, int n_in,
                              void* d_out, int out_size, void* d_ws, size_t ws_size,
                              hipStream_t stream) {
  const float* x      = (const float*)d_in[0];
  const float* ln_w   = (const float*)d_in[1];
  const float* ln_b   = (const float*)d_in[2];
  const float* A_log  = (const float*)d_in[3];
  const float* B_mat  = (const float*)d_in[4];
  const float* C_mat  = (const float*)d_in[5];
  const float* D_vec  = (const float*)d_in[6];
  const float* out_w  = (const float*)d_in[7];
  const float* out_b  = (const float*)d_in[8];
  const float* ln2_w  = (const float*)d_in[9];
  const float* ln2_b  = (const float*)d_in[10];
  const float* ffn1_w = (const float*)d_in[11];
  const float* ffn1_b = (const float*)d_in[12];
  const float* ffn2_w = (const float*)d_in[13];
  const float* ffn2_b = (const float*)d_in[14];
  float* out = (float*)d_out;

  char* ws = (char*)d_ws;
  const size_t MB = 1u << 20;
  float*          x1    = (float*)(ws);                    // 32MB (GEMM1 out)
  unsigned short* ybf   = (unsigned short*)(ws + 32*MB);   // 16MB; reused as xn2
  unsigned short* hdn   = (unsigned short*)(ws + 48*MB);   // 64MB
  unsigned short* w1b   = (unsigned short*)(ws + 112*MB);  // 2MB
  unsigned short* w2b   = (unsigned short*)(ws + 114*MB);  // 8MB
  unsigned short* w3b   = (unsigned short*)(ws + 122*MB);  // 8MB
  float*          hend  = (float*)(ws + 130*MB);           // 8MB
  float*          carry = (float*)(ws + 138*MB);           // 8MB
  float2*         stats = (float2*)(ws + 146*MB);          // 64KB

  // weights -> bf16
  cvt_bf16<<<(D_MODEL*D_MODEL/4)/256, 256, 0, stream>>>(out_w,  w1b, D_MODEL*D_MODEL/4);
  cvt_bf16<<<(H_FFN*D_MODEL/4)/256,  256, 0, stream>>>(ffn1_w, w2b, H_FFN*D_MODEL/4);
  cvt_bf16<<<(H_FFN*D_MODEL/4)/256,  256, 0, stream>>>(ffn2_w, w3b, H_FFN*D_MODEL/4);

  // LN1 stats (normalize fused into scan)
  ln_stats<<<M_ROWS, 256, 0, stream>>>(x, stats);

  // SSM scan -> ybf = silu(y) bf16
  dim3 gscan(D_MODEL/256, NCHUNK, BATCH);
  scan_phase1<<<gscan, 256, 0, stream>>>(x, stats, ln_w, ln_b, A_log, B_mat, hend);
  scan_phase2<<<(BATCH*D_MODEL*N_STATE)/256, 256, 0, stream>>>(A_log, hend, carry);
  scan_phase3<<<gscan, 256, 0, stream>>>(x, stats, ln_w, ln_b, A_log, B_mat, C_mat,
                                         D_vec, carry, ybf);

  // GEMM1: x1 = x + silu_y @ out_w^T + out_b  (BM=128: grid 64x4=256)
  gemm_hk<128, 0, true, float><<<dim3((M_ROWS/128)*(D_MODEL/256)), 512, 0, stream>>>(
      ybf, w1b, out_b, x, x1, M_ROWS, D_MODEL, D_MODEL);

  // LN2: xn2 = LN(x1) bf16 (into ybf buffer)
  ln_kernel_bf16<<<M_ROWS, 256, 0, stream>>>(x1, ln2_w, ln2_b, ybf);

  // GEMM2: hdn = gelu(xn2 @ ffn1^T + ffn1_b) bf16  (BM=256: grid 32x16=512)
  gemm_hk<256, 1, false, unsigned short><<<dim3((M_ROWS/256)*(H_FFN/256)), 512, 0, stream>>>(
      ybf, w2b, ffn1_b, nullptr, hdn, M_ROWS, H_FFN, D_MODEL);

  // GEMM3: out = x1 + hdn @ ffn2^T + ffn2_b  (BM=128: grid 64x4=256)
  gemm_hk<128, 0, true, float><<<dim3((M_ROWS/128)*(D_MODEL/256)), 512, 0, stream>>>(
      hdn, w3b, ffn2_b, x1, out, M_ROWS, D_MODEL, H_FFN);
}

// Round 9
// 298.382 us; speedup vs baseline: 1.1629x; 1.0301x over previous
//
#include <hip/hip_runtime.h>
#include <hip/hip_bf16.h>
#include <stdint.h>

#define D_MODEL 1024
#define N_STATE 16
#define BATCH   4
#define SEQ     2048
#define M_ROWS  (BATCH*SEQ)      // 8192
#define H_FFN   (4*D_MODEL)      // 4096
#define NCHUNK  32
#define TCHUNK  (SEQ/NCHUNK)     // 64

typedef __attribute__((ext_vector_type(8))) short short8;
typedef __attribute__((ext_vector_type(4))) float f32x4;

// ---------- helpers ----------
__device__ __forceinline__ unsigned short f2bf(float f) {
  unsigned int u = __builtin_bit_cast(unsigned int, f);
  u += 0x7FFFu + ((u >> 16) & 1u);
  return (unsigned short)(u >> 16);
}

__device__ __forceinline__ void gload_lds16(const void* g, void* l) {
  __builtin_amdgcn_global_load_lds(
      (const __attribute__((address_space(1))) void*)g,
      (__attribute__((address_space(3))) void*)l,
      16, 0, 0);
}

// ---------- fp32 -> bf16 weight conversion ----------
__global__ __launch_bounds__(256)
void cvt_bf16(const float* __restrict__ in, unsigned short* __restrict__ out, int n4) {
  int i = blockIdx.x * 256 + threadIdx.x;
  if (i >= n4) return;
  float4 v = reinterpret_cast<const float4*>(in)[i];
  ushort4 o = { f2bf(v.x), f2bf(v.y), f2bf(v.z), f2bf(v.w) };
  reinterpret_cast<ushort4*>(out)[i] = o;
}

// ---------- LN stats only: per row -> (mu, inv_sigma) ----------
__global__ __launch_bounds__(256)
void ln_stats(const float* __restrict__ in, float2* __restrict__ stats) {
  const int row = blockIdx.x;
  const int tid = threadIdx.x;
  const float4 v = reinterpret_cast<const float4*>(in + (size_t)row * D_MODEL)[tid];
  float s  = v.x + v.y + v.z + v.w;
  float ss = v.x*v.x + v.y*v.y + v.z*v.z + v.w*v.w;
  #pragma unroll
  for (int o = 32; o > 0; o >>= 1) {
    s  += __shfl_down(s, o, 64);
    ss += __shfl_down(ss, o, 64);
  }
  __shared__ float red[8];
  const int wv = tid >> 6;
  if ((tid & 63) == 0) { red[wv] = s; red[4 + wv] = ss; }
  __syncthreads();
  if (tid == 0) {
    s  = red[0] + red[1] + red[2] + red[3];
    ss = red[4] + red[5] + red[6] + red[7];
    const float mu  = s * (1.0f / D_MODEL);
    const float inv = rsqrtf(ss * (1.0f / D_MODEL) - mu * mu + 1e-5f);
    stats[row] = make_float2(mu, inv);
  }
}

// ---------- full LayerNorm (LN2), bf16 out ----------
__global__ __launch_bounds__(256)
void ln_kernel_bf16(const float* __restrict__ in, const float* __restrict__ gamma,
                    const float* __restrict__ beta, unsigned short* __restrict__ outp) {
  const int row = blockIdx.x;
  const int tid = threadIdx.x;
  const float4 v = reinterpret_cast<const float4*>(in + (size_t)row * D_MODEL)[tid];
  float s  = v.x + v.y + v.z + v.w;
  float ss = v.x*v.x + v.y*v.y + v.z*v.z + v.w*v.w;
  #pragma unroll
  for (int o = 32; o > 0; o >>= 1) {
    s  += __shfl_down(s, o, 64);
    ss += __shfl_down(ss, o, 64);
  }
  __shared__ float red[8];
  const int wv = tid >> 6;
  if ((tid & 63) == 0) { red[wv] = s; red[4 + wv] = ss; }
  __syncthreads();
  s  = red[0] + red[1] + red[2] + red[3];
  ss = red[4] + red[5] + red[6] + red[7];
  const float mu  = s * (1.0f / D_MODEL);
  const float inv = rsqrtf(ss * (1.0f / D_MODEL) - mu * mu + 1e-5f);
  const float4 g4 = reinterpret_cast<const float4*>(gamma)[tid];
  const float4 b4 = reinterpret_cast<const float4*>(beta)[tid];
  ushort4 o = { f2bf((v.x - mu) * inv * g4.x + b4.x),
                f2bf((v.y - mu) * inv * g4.y + b4.y),
                f2bf((v.z - mu) * inv * g4.z + b4.z),
                f2bf((v.w - mu) * inv * g4.w + b4.w) };
  reinterpret_cast<ushort4*>(outp + (size_t)row * D_MODEL)[tid] = o;
}

// ---------- SSM scan, chunked (3 phases), LN1 fused via stats ----------
__global__ __launch_bounds__(256)
void scan_phase1(const float* __restrict__ x, const float2* __restrict__ stats,
                 const float* __restrict__ ln_w, const float* __restrict__ ln_b,
                 const float* __restrict__ A_log, const float* __restrict__ B_mat,
                 float* __restrict__ hend) {
  const int d = blockIdx.x * 256 + threadIdx.x;
  const int c = blockIdx.y;
  const int b = blockIdx.z;
  float a[16], Bm[16], h[16];
  const float4* Ar = reinterpret_cast<const float4*>(A_log + d * 16);
  const float4* Br = reinterpret_cast<const float4*>(B_mat + d * 16);
  #pragma unroll
  for (int i = 0; i < 4; i++) {
    const float4 av = Ar[i], bv = Br[i];
    a[4*i+0]=av.x; a[4*i+1]=av.y; a[4*i+2]=av.z; a[4*i+3]=av.w;
    Bm[4*i+0]=bv.x; Bm[4*i+1]=bv.y; Bm[4*i+2]=bv.z; Bm[4*i+3]=bv.w;
  }
  #pragma unroll
  for (int n = 0; n < 16; n++) { a[n] = 1.0f/(1.0f+__expf(-a[n])); h[n] = 0.0f; }
  const float gd = ln_w[d], bd = ln_b[d];

  const float* xp = x + ((size_t)b * SEQ + (size_t)c * TCHUNK) * D_MODEL + d;
  const float2* sp = stats + (size_t)b * SEQ + (size_t)c * TCHUNK;
  #pragma unroll 4
  for (int t = 0; t < TCHUNK; ++t) {
    const float2 st = sp[t];
    const float xv = (xp[(size_t)t * D_MODEL] - st.x) * st.y * gd + bd;
    #pragma unroll
    for (int n = 0; n < 16; n++) h[n] = a[n]*h[n] + Bm[n]*xv;
  }
  float* hp = hend + (((size_t)b * NCHUNK + c) * D_MODEL + d) * 16;
  #pragma unroll
  for (int i = 0; i < 4; i++) {
    float4 o = { h[4*i+0], h[4*i+1], h[4*i+2], h[4*i+3] };
    reinterpret_cast<float4*>(hp)[i] = o;
  }
}

__global__ __launch_bounds__(256)
void scan_phase2(const float* __restrict__ A_log, const float* __restrict__ hend,
                 float* __restrict__ carry) {
  const int idx = blockIdx.x * 256 + threadIdx.x;
  const int n = idx & 15;
  const int d = (idx >> 4) & (D_MODEL - 1);
  const int b = idx >> 14;
  const float a = 1.0f/(1.0f+__expf(-A_log[d*16+n]));
  float aT = a;
  #pragma unroll
  for (int i = 0; i < 6; i++) aT *= aT;   // a^64
  float cv = 0.0f;
  for (int c = 0; c < NCHUNK; c++) {
    const size_t off = (((size_t)b * NCHUNK + c) * D_MODEL + d) * 16 + n;
    carry[off] = cv;
    cv = aT * cv + hend[off];
  }
}

__global__ __launch_bounds__(256)
void scan_phase3(const float* __restrict__ x, const float2* __restrict__ stats,
                 const float* __restrict__ ln_w, const float* __restrict__ ln_b,
                 const float* __restrict__ A_log, const float* __restrict__ B_mat,
                 const float* __restrict__ C_mat, const float* __restrict__ D_vec,
                 const float* __restrict__ carry, unsigned short* __restrict__ ybf) {
  const int d = blockIdx.x * 256 + threadIdx.x;
  const int c = blockIdx.y;
  const int b = blockIdx.z;
  float a[16], Bm[16], Cm[16], h[16];
  const float4* Ar = reinterpret_cast<const float4*>(A_log + d * 16);
  const float4* Br = reinterpret_cast<const float4*>(B_mat + d * 16);
  const float4* Cr = reinterpret_cast<const float4*>(C_mat + d * 16);
  const float4* Hr = reinterpret_cast<const float4*>(carry + (((size_t)b * NCHUNK + c) * D_MODEL + d) * 16);
  #pragma unroll
  for (int i = 0; i < 4; i++) {
    const float4 av = Ar[i], bv = Br[i], cv = Cr[i], hv = Hr[i];
    a[4*i+0]=av.x; a[4*i+1]=av.y; a[4*i+2]=av.z; a[4*i+3]=av.w;
    Bm[4*i+0]=bv.x; Bm[4*i+1]=bv.y; Bm[4*i+2]=bv.z; Bm[4*i+3]=bv.w;
    Cm[4*i+0]=cv.x; Cm[4*i+1]=cv.y; Cm[4*i+2]=cv.z; Cm[4*i+3]=cv.w;
    h[4*i+0]=hv.x; h[4*i+1]=hv.y; h[4*i+2]=hv.z; h[4*i+3]=hv.w;
  }
  #pragma unroll
  for (int n = 0; n < 16; n++) a[n] = 1.0f/(1.0f+__expf(-a[n]));
  const float Dv = D_vec[d];
  const float gd = ln_w[d], bd = ln_b[d];

  const float* xp = x + ((size_t)b * SEQ + (size_t)c * TCHUNK) * D_MODEL + d;
  const float2* sp = stats + (size_t)b * SEQ + (size_t)c * TCHUNK;
  unsigned short* yp = ybf + ((size_t)b * SEQ + (size_t)c * TCHUNK) * D_MODEL + d;
  #pragma unroll 4
  for (int t = 0; t < TCHUNK; ++t) {
    const float2 st = sp[t];
    const float xv = (xp[(size_t)t * D_MODEL] - st.x) * st.y * gd + bd;
    float y = Dv * xv;
    #pragma unroll
    for (int n = 0; n < 16; n++) {
      h[n] = a[n]*h[n] + Bm[n]*xv;
      y += Cm[n]*h[n];
    }
    yp[(size_t)t * D_MODEL] = f2bf(y / (1.0f + __expf(-y)));
  }
}

// ---------- m97-structure bf16 MFMA GEMM (multi-block overlap) ----------
// C[M,N] = epi(A[M,K] @ Bt[N,K]^T + bias). 128x128 tile, BK=64,
// 256 thr = 4 waves (2x2), per-wave output 64x64 (4x4 16x16x32 frags).
// Single-buffered 32KB LDS -> 4 blocks/CU: one block's barrier/vmcnt drain
// is hidden by the other blocks' compute (m114 implicit overlap). Simple
// 2-barrier K-loop; no inline-asm waits, no setprio (m190: hurts here).
// XOR-swizzled LDS (conflict-free), XCD-aware block swizzle, slab epilogue.
template<int ACT, bool RES, typename OutT>
__global__ __launch_bounds__(256, 4)
void gemm_m97(const unsigned short* __restrict__ A, const unsigned short* __restrict__ Bt,
              const float* __restrict__ bias, const float* __restrict__ res,
              OutT* __restrict__ C, int M, int N, int K) {
  __shared__ unsigned short Sh[2 * 128 * 64];   // 32KB: A tile then B tile
  unsigned short* As = Sh;
  unsigned short* Bs = Sh + 128 * 64;

  const int tid = threadIdx.x;
  const int l = tid & 63, w = tid >> 6;
  const int wr = w >> 1, wn = w & 1;

  // XCD-aware chunked swizzle (grids are multiples of 8)
  int bid = blockIdx.x;
  const int cpx = gridDim.x >> 3;
  bid = (bid & 7) * cpx + (bid >> 3);
  const int nbx = N / 128;
  const int bn = (bid % nbx) * 128;
  const int bm = (bid / nbx) * 128;

  // staging: wave w stages rows 32w..32w+31 of each tile (4 slabs x 8 rows).
  // lane l -> row +(l>>3), LDS byte (l&7)*16 (linear dest). Source byte
  // pre-swizzled so LDS[row][kb] = global[row][kb ^ ((row&7)<<4)].
  const int prow = l >> 3;
  const int skb  = ((l & 7) ^ prow) << 4;
  const char* Ag = (const char*)A  + ((size_t)(bm + 32 * w + prow) * K) * 2 + skb;
  const char* Bg = (const char*)Bt + ((size_t)(bn + 32 * w + prow) * K) * 2 + skb;

#define STA(q, k0) gload_lds16(Ag + ((size_t)(8*(q))*K + (k0))*2, (char*)As + w*4096 + (q)*1024)
#define STB(q, k0) gload_lds16(Bg + ((size_t)(8*(q))*K + (k0))*2, (char*)Bs + w*4096 + (q)*1024)

  // read-side: frag addr = base + row*128 + ((kk*64 + (l>>4)*16) ^ ((l&7)<<4))
  const int xk0 = ((l >> 4) * 16) ^ ((l & 7) << 4);
  const int xk1 = (64 + (l >> 4) * 16) ^ ((l & 7) << 4);
  const char* ArB = (const char*)As + (wr * 64 + (l & 15)) * 128;
  const char* BrB = (const char*)Bs + (wn * 64 + (l & 15)) * 128;

  f32x4 acc[4][4] = {};

  for (int k0 = 0; k0 < K; k0 += 64) {
    STA(0, k0); STA(1, k0); STA(2, k0); STA(3, k0);
    STB(0, k0); STB(1, k0); STB(2, k0); STB(3, k0);
    __syncthreads();   // drains vmcnt: tile landed
    #pragma unroll
    for (int kk = 0; kk < 2; ++kk) {
      const int xk = kk ? xk1 : xk0;
      short8 af[4], bv[4];
      #pragma unroll
      for (int m = 0; m < 4; ++m)
        af[m] = *reinterpret_cast<const short8*>(ArB + m * 2048 + xk);
      #pragma unroll
      for (int n = 0; n < 4; ++n)
        bv[n] = *reinterpret_cast<const short8*>(BrB + n * 2048 + xk);
      #pragma unroll
      for (int m = 0; m < 4; ++m)
        #pragma unroll
        for (int n = 0; n < 4; ++n)
          acc[m][n] = __builtin_amdgcn_mfma_f32_16x16x32_bf16(af[m], bv[n], acc[m][n], 0, 0, 0);
    }
    __syncthreads();   // reads done before next tile's writes
  }
#undef STA
#undef STB

  // ---- coalesced epilogue via wave-private LDS slab (reuses Sh) ----
  constexpr int LPAD = 65;                      // floats per slab row (+1 pad)
  float* slab = (float*)((char*)Sh + w * 4352); // 4 waves x 4352B <= 32KB
  const int fr = (l >> 4) * 4;
  const int fc = l & 15;
  const int rdrow = l >> 4;                     // 16 float4 chunks per row
  const int rdchk = l & 15;
  const int colg0 = bn + wn * 64;
  float bvn[4];
  #pragma unroll
  for (int n = 0; n < 4; ++n) bvn[n] = bias[colg0 + n * 16 + fc];

  #pragma unroll
  for (int m = 0; m < 4; ++m) {
    asm volatile("s_waitcnt lgkmcnt(0)" ::: "memory");  // prev readback done
    #pragma unroll
    for (int n = 0; n < 4; ++n)
      #pragma unroll
      for (int r = 0; r < 4; ++r)
        slab[(fr + r) * LPAD + n * 16 + fc] = acc[m][n][r] + bvn[n];
    asm volatile("s_waitcnt lgkmcnt(0)" ::: "memory");  // writes visible to wave
    const int row0 = bm + wr * 64 + m * 16;
    #pragma unroll
    for (int p = 0; p < 4; ++p) {
      const int row = p * 4 + rdrow;
      float4 v4 = *reinterpret_cast<const float4*>(&slab[row * LPAD + rdchk * 4]);
      const size_t idx = (size_t)(row0 + row) * N + colg0 + rdchk * 4;
      float vv[4] = { v4.x, v4.y, v4.z, v4.w };
      if (ACT == 1) {
        #pragma unroll
        for (int j = 0; j < 4; ++j)
          vv[j] = 0.5f * vv[j] * (1.0f + erff(vv[j] * 0.70710678118f));
      }
      if (RES) {
        const float4 r4 = *reinterpret_cast<const float4*>(&res[idx]);
        vv[0] += r4.x; vv[1] += r4.y; vv[2] += r4.z; vv[3] += r4.w;
      }
      if constexpr (sizeof(OutT) == 2) {
        ushort4 o = { f2bf(vv[0]), f2bf(vv[1]), f2bf(vv[2]), f2bf(vv[3]) };
        *reinterpret_cast<ushort4*>(&C[idx]) = o;
      } else {
        float4 o = { vv[0], vv[1], vv[2], vv[3] };
        *reinterpret_cast<float4*>(&C[idx]) = o;
      }
    }
  }
}

// ---------- launch ----------
extern "C" void kernel_launch(void* const* d_in, const int* in_sizes, int n_in,
                              void* d_out, int out_size, void* d_ws, size_t ws_size,
                              hipStream_t stream) {
  const float* x      = (const float*)d_in[0];
  const float* ln_w   = (const float*)d_in[1];
  const float* ln_b   = (const float*)d_in[2];
  const float* A_log  = (const float*)d_in[3];
  const float* B_mat  = (const float*)d_in[4];
  const float* C_mat  = (const float*)d_in[5];
  const float* D_vec  = (const float*)d_in[6];
  const float* out_w  = (const float*)d_in[7];
  const float* out_b  = (const float*)d_in[8];
  const float* ln2_w  = (const float*)d_in[9];
  const float* ln2_b  = (const float*)d_in[10];
  const float* ffn1_w = (const float*)d_in[11];
  const float* ffn1_b = (const float*)d_in[12];
  const float* ffn2_w = (const float*)d_in[13];
  const float* ffn2_b = (const float*)d_in[14];
  float* out = (float*)d_out;

  char* ws = (char*)d_ws;
  const size_t MB = 1u << 20;
  float*          x1    = (float*)(ws);                    // 32MB (GEMM1 out)
  unsigned short* ybf   = (unsigned short*)(ws + 32*MB);   // 16MB; reused as xn2
  unsigned short* hdn   = (unsigned short*)(ws + 48*MB);   // 64MB
  unsigned short* w1b   = (unsigned short*)(ws + 112*MB);  // 2MB
  unsigned short* w2b   = (unsigned short*)(ws + 114*MB);  // 8MB
  unsigned short* w3b   = (unsigned short*)(ws + 122*MB);  // 8MB
  float*          hend  = (float*)(ws + 130*MB);           // 8MB
  float*          carry = (float*)(ws + 138*MB);           // 8MB
  float2*         stats = (float2*)(ws + 146*MB);          // 64KB

  // weights -> bf16
  cvt_bf16<<<(D_MODEL*D_MODEL/4)/256, 256, 0, stream>>>(out_w,  w1b, D_MODEL*D_MODEL/4);
  cvt_bf16<<<(H_FFN*D_MODEL/4)/256,  256, 0, stream>>>(ffn1_w, w2b, H_FFN*D_MODEL/4);
  cvt_bf16<<<(H_FFN*D_MODEL/4)/256,  256, 0, stream>>>(ffn2_w, w3b, H_FFN*D_MODEL/4);

  // LN1 stats (normalize fused into scan)
  ln_stats<<<M_ROWS, 256, 0, stream>>>(x, stats);

  // SSM scan -> ybf = silu(y) bf16
  dim3 gscan(D_MODEL/256, NCHUNK, BATCH);
  scan_phase1<<<gscan, 256, 0, stream>>>(x, stats, ln_w, ln_b, A_log, B_mat, hend);
  scan_phase2<<<(BATCH*D_MODEL*N_STATE)/256, 256, 0, stream>>>(A_log, hend, carry);
  scan_phase3<<<gscan, 256, 0, stream>>>(x, stats, ln_w, ln_b, A_log, B_mat, C_mat,
                                         D_vec, carry, ybf);

  // GEMM1: x1 = x + silu_y @ out_w^T + out_b  (grid 64x8=512)
  gemm_m97<0, true, float><<<dim3((M_ROWS/128)*(D_MODEL/128)), 256, 0, stream>>>(
      ybf, w1b, out_b, x, x1, M_ROWS, D_MODEL, D_MODEL);

  // LN2: xn2 = LN(x1) bf16 (into ybf buffer)
  ln_kernel_bf16<<<M_ROWS, 256, 0, stream>>>(x1, ln2_w, ln2_b, ybf);

  // GEMM2: hdn = gelu(xn2 @ ffn1^T + ffn1_b) bf16  (grid 64x32=2048)
  gemm_m97<1, false, unsigned short><<<dim3((M_ROWS/128)*(H_FFN/128)), 256, 0, stream>>>(
      ybf, w2b, ffn1_b, nullptr, hdn, M_ROWS, H_FFN, D_MODEL);

  // GEMM3: out = x1 + hdn @ ffn2^T + ffn2_b  (grid 64x8=512)
  gemm_m97<0, true, float><<<dim3((M_ROWS/128)*(D_MODEL/128)), 256, 0, stream>>>(
      hdn, w3b, ffn2_b, x1, out, M_ROWS, D_MODEL, H_FFN);
}